// Round 12
// baseline (87.575 us; speedup 1.0000x reference)
//
#include <hip/hip_runtime.h>

#define H 128
#define W 128
#define C 64
#define HW (H * W)
#define RAD 2
#define KD 5
#define KK 25

#define TS 8              // 8x8 pixel tile
#define HROWS 12          // halo rows (y0-2 .. y0+9)
#define RSTR 16           // u32 per halo row (x0-4 .. x0+11), float4-aligned
#define PSTR 200          // 12*16=192 +8 pad: cs-plane bank phase = 8*plane mod 32
#define RPAIRS 16         // channel-pairs staged per round
#define LDSU (RPAIRS * PSTR) // 3200 u32 = 12.8 KB -> 8+ blocks/CU

#define SCALE_L2E 0.18033688011112042f  // (1/sqrt(64)) * log2(e)

typedef _Float16 h2 __attribute__((ext_vector_type(2)));
typedef __fp16 fp16v2 __attribute__((ext_vector_type(2)));

__device__ __forceinline__ float dot2acc(h2 a, h2 w, float acc)
{
#if __has_builtin(__builtin_amdgcn_fdot2)
    return __builtin_amdgcn_fdot2(a, w, acc, false);   // v_dot2_f32_f16
#else
    return fmaf((float)a.x, (float)w.x, fmaf((float)a.y, (float)w.y, acc));
#endif
}

__device__ __forceinline__ uint32_t pkh2(float lo, float hi)
{
#if __has_builtin(__builtin_amdgcn_cvt_pkrtz)
    fp16v2 t = __builtin_amdgcn_cvt_pkrtz(lo, hi);
    return __builtin_bit_cast(uint32_t, t);
#else
    h2 t; t.x = (_Float16)lo; t.y = (_Float16)hi;
    return __builtin_bit_cast(uint32_t, t);
#endif
}

__device__ __forceinline__ h2 bch2(uint32_t u) { return __builtin_bit_cast(h2, u); }

// cs-group reduction: cs = lane bits 4..5 -> xor16 + xor32 sums the 4 groups.
__device__ __forceinline__ float cs_reduce(float x)
{
    x += __shfl_xor(x, 16, 64);
    x += __shfl_xor(x, 32, 64);
    return x;
}

// exp2-domain softmax-expectation, no max-subtraction (|corr*scale| small;
// softmax shift-invariant; masked taps contribute exactly 0).
template<bool MASKED>
__device__ __forceinline__ float2 softmax_eo(const float (&cr)[KK], int xx, int yy)
{
    float sum = 0.f, ox = 0.f, oy = 0.f;
#pragma unroll
    for (int ky = 0; ky < KD; ++ky) {
#pragma unroll
        for (int kx = 0; kx < KD; ++kx) {
            int k = ky * KD + kx;
            float e = exp2f(cr[k] * SCALE_L2E);
            if (MASKED) {
                int sxx = xx + kx - RAD, syy = yy + ky - RAD;
                bool valid = (sxx >= 0) && (sxx < W) && (syy >= 0) && (syy < H);
                e = valid ? e : 0.f;
            }
            sum += e;
            ox += e * (float)(kx - RAD);
            oy += e * (float)(ky - RAD);
        }
    }
    float inv = 1.f / sum;
    return make_float2(ox * inv, oy * inv);
}

__global__ __launch_bounds__(256, 8)
void bam_corr_softmax_kernel(const float* __restrict__ f0,
                             const float* __restrict__ f1,
                             const float* __restrict__ f2,
                             float* __restrict__ out)
{
    __shared__ uint32_t lds[LDSU];

    const int tid   = threadIdx.x;
    const int lane  = tid & 63;
    const int wav   = tid >> 6;        // 0..3
    const int cs    = lane >> 4;       // channel group 0..3 (4 pairs/round)
    const int pw    = lane & 15;       // pixel in wave
    const int pixel = wav * 16 + pw;   // 0..63
    const int ly    = pixel >> 3;      // 0..7
    const int lx    = pixel & 7;       // 0..7

    // XCD banding: band = blockIdx.x % 8 -> 16-row y-band per XCD L2 (~3.1MB);
    // consecutive blocks on an XCD cycle the 8 (v,b) jobs of the same tile.
    const int i     = blockIdx.x;
    const int band  = i & 7;
    const int j     = i >> 3;
    const int img   = j & 7;           // v*2 + b
    const int t     = j >> 3;          // 0..31
    const int tileX = t & 15;          // 0..15
    const int tileY = band * 2 + (t >> 4); // 0..15

    const int v = img >> 1;
    const int b = img & 1;

    const float* A;
    const float* Bf;
    if (v == 0)      { A = f0; Bf = f2; }
    else if (v == 1) { A = f1; Bf = f2; }
    else if (v == 2) { A = f2; Bf = f0; }
    else             { A = f2; Bf = f1; }

    const int x0 = tileX * TS;
    const int y0 = tileY * TS;
    const int x  = x0 + lx;
    const int y  = y0 + ly;

    const float* Arow  = A + (size_t)b * C * HW + (size_t)(y * W + x);
    const float* Bbase = Bf + (size_t)b * C * HW;

    const bool interior = (tileX >= 1) && (tileX <= 14) && (tileY >= 1) && (tileY <= 14);

    float acc[KK];
#pragma unroll
    for (int k = 0; k < KK; ++k) acc[k] = 0.f;

    for (int r = 0; r < 2; ++r) {
        if (r) __syncthreads();        // compute(r-1) done before LDS overwrite

        // ---- stage 16 pair-planes (12 rows x 16 u32) as f16-pair uint4 ----
        // 16 planes * 12 rows * 4 chunks = 768 = 3 per thread exactly
#pragma unroll
        for (int it = 0; it < 3; ++it) {
            int q   = tid + it * 256;
            int p   = q / 48;          // plane-in-round 0..15
            int rem = q - p * 48;
            int row = rem >> 2;
            int c4  = rem & 3;
            int gy  = y0 - 2 + row;
            int gx  = x0 - 4 + c4 * 4;
            int ch0 = 2 * (r * RPAIRS + p);
            float4 lo, hi;
            if (interior) {
                const float* p0 = Bbase + (size_t)ch0 * HW + (size_t)(gy * W + gx);
                lo = *reinterpret_cast<const float4*>(p0);
                hi = *reinterpret_cast<const float4*>(p0 + HW);
            } else {
                float lv[4], hv[4];
#pragma unroll
                for (int e = 0; e < 4; ++e) {
                    int gxe = gx + e;
                    bool ok = (gy >= 0) && (gy < H) && (gxe >= 0) && (gxe < W);
                    size_t offg = (size_t)ch0 * HW + (size_t)(ok ? gy * W + gxe : 0);
                    lv[e] = ok ? Bbase[offg] : 0.f;
                    hv[e] = ok ? Bbase[offg + HW] : 0.f;
                }
                lo = make_float4(lv[0], lv[1], lv[2], lv[3]);
                hi = make_float4(hv[0], hv[1], hv[2], hv[3]);
            }
            uint4 wq = make_uint4(pkh2(lo.x, hi.x), pkh2(lo.y, hi.y),
                                  pkh2(lo.z, hi.z), pkh2(lo.w, hi.w));
            *reinterpret_cast<uint4*>(&lds[p * PSTR + row * RSTR + c4 * 4]) = wq;
        }
        __syncthreads();

        // ---- compute: 4 pairs per cs-group this round, 1 output/thread ----
#pragma unroll
        for (int c = 0; c < 4; ++c) {
            const int plane = cs * 4 + c;
            const int P = r * RPAIRS + plane;
            const float* ap = Arow + (size_t)(2 * P) * HW;
            h2 a = bch2(pkh2(ap[0], ap[HW]));   // (ch 2P, ch 2P+1) at (x,y)
            // storage col (lx+2) == global col x-2 (window start)
            const uint32_t* bp = &lds[plane * PSTR + ly * RSTR + lx + 2];
#pragma unroll
            for (int rr = 0; rr < KD; ++rr) {
                const uint32_t* rp = bp + rr * RSTR;
                uint32_t w0 = rp[0], w1 = rp[1], w2 = rp[2], w3 = rp[3], w4 = rp[4];
                const int kb = rr * KD;
                acc[kb + 0] = dot2acc(a, bch2(w0), acc[kb + 0]);
                acc[kb + 1] = dot2acc(a, bch2(w1), acc[kb + 1]);
                acc[kb + 2] = dot2acc(a, bch2(w2), acc[kb + 2]);
                acc[kb + 3] = dot2acc(a, bch2(w3), acc[kb + 3]);
                acc[kb + 4] = dot2acc(a, bch2(w4), acc[kb + 4]);
            }
        }
    }

    // ---- reduce the 4 channel-group partials ----
#pragma unroll
    for (int k = 0; k < KK; ++k) acc[k] = cs_reduce(acc[k]);

    // ---- softmax + expected offset (mask only on border tiles) ----
    float2 r0 = interior ? softmax_eo<false>(acc, x, y)
                         : softmax_eo<true>(acc, x, y);

    if (cs == 0) {
        size_t ob = ((size_t)img * 2) * HW + (size_t)(y * W + x);
        out[ob]      = r0.x;
        out[ob + HW] = r0.y;
    }
}

extern "C" void kernel_launch(void* const* d_in, const int* in_sizes, int n_in,
                              void* d_out, int out_size, void* d_ws, size_t ws_size,
                              hipStream_t stream)
{
    const float* f0 = (const float*)d_in[0];
    const float* f1 = (const float*)d_in[1];
    const float* f2 = (const float*)d_in[2];
    float* out = (float*)d_out;

    dim3 block(256, 1, 1);
    dim3 grid(2048, 1, 1); // 8 bands x 8 img x 32 tiles of 8x8
    bam_corr_softmax_kernel<<<grid, block, 0, stream>>>(f0, f1, f2, out);
}

// Round 13
// 84.283 us; speedup vs baseline: 1.0391x; 1.0391x over previous
//
#include <hip/hip_runtime.h>

#define H 128
#define W 128
#define C 64
#define HW (H * W)
#define RAD 2
#define KD 5
#define KK 25

#define TS 8              // 8x8 pixel tile
#define HROWS 12          // halo rows (y0-2 .. y0+9)
#define RSTR 16           // u32 per halo row (x0-4 .. x0+11), float4-aligned
#define PSTR 200          // 12*16=192 +8 pad
#define RPAIRS 16         // channel-pairs staged per round
#define LDSU (RPAIRS * PSTR) // 3200 u32 = 12.8 KB -> 6 blocks/CU fits easily

#define SCALE_L2E 0.18033688011112042f  // (1/sqrt(64)) * log2(e)

typedef _Float16 h2 __attribute__((ext_vector_type(2)));
typedef __fp16 fp16v2 __attribute__((ext_vector_type(2)));

__device__ __forceinline__ float dot2acc(h2 a, h2 w, float acc)
{
#if __has_builtin(__builtin_amdgcn_fdot2)
    return __builtin_amdgcn_fdot2(a, w, acc, false);   // v_dot2_f32_f16
#else
    return fmaf((float)a.x, (float)w.x, fmaf((float)a.y, (float)w.y, acc));
#endif
}

__device__ __forceinline__ uint32_t pkh2(float lo, float hi)
{
#if __has_builtin(__builtin_amdgcn_cvt_pkrtz)
    fp16v2 t = __builtin_amdgcn_cvt_pkrtz(lo, hi);
    return __builtin_bit_cast(uint32_t, t);
#else
    h2 t; t.x = (_Float16)lo; t.y = (_Float16)hi;
    return __builtin_bit_cast(uint32_t, t);
#endif
}

__device__ __forceinline__ h2 bch2(uint32_t u) { return __builtin_bit_cast(h2, u); }

// cs-group reduction: cs = lane bits 4..5 -> xor16 + xor32 sums the 4 groups.
__device__ __forceinline__ float cs_reduce(float x)
{
    x += __shfl_xor(x, 16, 64);
    x += __shfl_xor(x, 32, 64);
    return x;
}

// exp2-domain softmax-expectation, no max-subtraction (|corr*scale| small;
// softmax shift-invariant; masked taps contribute exactly 0).
template<bool MASKED>
__device__ __forceinline__ float2 softmax_eo(const float (&cr)[KK], int xx, int yy)
{
    float sum = 0.f, ox = 0.f, oy = 0.f;
#pragma unroll
    for (int ky = 0; ky < KD; ++ky) {
#pragma unroll
        for (int kx = 0; kx < KD; ++kx) {
            int k = ky * KD + kx;
            float e = exp2f(cr[k] * SCALE_L2E);
            if (MASKED) {
                int sxx = xx + kx - RAD, syy = yy + ky - RAD;
                bool valid = (sxx >= 0) && (sxx < W) && (syy >= 0) && (syy < H);
                e = valid ? e : 0.f;
            }
            sum += e;
            ox += e * (float)(kx - RAD);
            oy += e * (float)(ky - RAD);
        }
    }
    float inv = 1.f / sum;
    return make_float2(ox * inv, oy * inv);
}

// launch_bounds(256, 6): VGPR cap 512/6 = 85 -- fits 25 f32 accumulators +
// temps WITHOUT spill (R12's cap of 64 at min-waves=8 spilled: WRITE 181MB).
// 6 blocks/CU * 4 waves = 24 waves/CU, 1.5x the 2-output family's 16.
__global__ __launch_bounds__(256, 6)
void bam_corr_softmax_kernel(const float* __restrict__ f0,
                             const float* __restrict__ f1,
                             const float* __restrict__ f2,
                             float* __restrict__ out)
{
    __shared__ uint32_t lds[LDSU];

    const int tid   = threadIdx.x;
    const int lane  = tid & 63;
    const int wav   = tid >> 6;        // 0..3
    const int cs    = lane >> 4;       // channel group 0..3 (4 pairs/round)
    const int pw    = lane & 15;       // pixel in wave
    const int pixel = wav * 16 + pw;   // 0..63
    const int ly    = pixel >> 3;      // 0..7
    const int lx    = pixel & 7;       // 0..7

    // XCD banding: band = blockIdx.x % 8 -> 16-row y-band per XCD L2 (~3.1MB);
    // consecutive blocks on an XCD cycle the 8 (v,b) jobs of the same tile.
    const int i     = blockIdx.x;
    const int band  = i & 7;
    const int j     = i >> 3;
    const int img   = j & 7;           // v*2 + b
    const int t     = j >> 3;          // 0..31
    const int tileX = t & 15;          // 0..15
    const int tileY = band * 2 + (t >> 4); // 0..15

    const int v = img >> 1;
    const int b = img & 1;

    const float* A;
    const float* Bf;
    if (v == 0)      { A = f0; Bf = f2; }
    else if (v == 1) { A = f1; Bf = f2; }
    else if (v == 2) { A = f2; Bf = f0; }
    else             { A = f2; Bf = f1; }

    const int x0 = tileX * TS;
    const int y0 = tileY * TS;
    const int x  = x0 + lx;
    const int y  = y0 + ly;

    const float* Arow  = A + (size_t)b * C * HW + (size_t)(y * W + x);
    const float* Bbase = Bf + (size_t)b * C * HW;

    const bool interior = (tileX >= 1) && (tileX <= 14) && (tileY >= 1) && (tileY <= 14);

    float acc[KK];
#pragma unroll
    for (int k = 0; k < KK; ++k) acc[k] = 0.f;

    for (int r = 0; r < 2; ++r) {
        if (r) __syncthreads();        // compute(r-1) done before LDS overwrite

        // ---- stage 16 pair-planes (12 rows x 16 u32) as f16-pair uint4 ----
        // 16 planes * 12 rows * 4 chunks = 768 = 3 per thread exactly
#pragma unroll
        for (int it = 0; it < 3; ++it) {
            int q   = tid + it * 256;
            int p   = q / 48;          // plane-in-round 0..15
            int rem = q - p * 48;
            int row = rem >> 2;
            int c4  = rem & 3;
            int gy  = y0 - 2 + row;
            int gx  = x0 - 4 + c4 * 4;
            int ch0 = 2 * (r * RPAIRS + p);
            float4 lo, hi;
            if (interior) {
                const float* p0 = Bbase + (size_t)ch0 * HW + (size_t)(gy * W + gx);
                lo = *reinterpret_cast<const float4*>(p0);
                hi = *reinterpret_cast<const float4*>(p0 + HW);
            } else {
                float lv[4], hv[4];
#pragma unroll
                for (int e = 0; e < 4; ++e) {
                    int gxe = gx + e;
                    bool ok = (gy >= 0) && (gy < H) && (gxe >= 0) && (gxe < W);
                    size_t offg = (size_t)ch0 * HW + (size_t)(ok ? gy * W + gxe : 0);
                    lv[e] = ok ? Bbase[offg] : 0.f;
                    hv[e] = ok ? Bbase[offg + HW] : 0.f;
                }
                lo = make_float4(lv[0], lv[1], lv[2], lv[3]);
                hi = make_float4(hv[0], hv[1], hv[2], hv[3]);
            }
            uint4 wq = make_uint4(pkh2(lo.x, hi.x), pkh2(lo.y, hi.y),
                                  pkh2(lo.z, hi.z), pkh2(lo.w, hi.w));
            *reinterpret_cast<uint4*>(&lds[p * PSTR + row * RSTR + c4 * 4]) = wq;
        }
        __syncthreads();

        // ---- compute: 4 pairs per cs-group this round, 1 output/thread ----
        // plane = c*4 + cs (interleaved): plane bank phase = 8*cs mod 32 ->
        // cs groups land on {0,8,16,24} -> every bank exactly 2 lanes (free).
        // (R12's plane = cs*4+c gave phase 0 for all cs -> 4-way conflict.)
#pragma unroll
        for (int c = 0; c < 4; ++c) {
            const int plane = c * 4 + cs;
            const int P = r * RPAIRS + plane;
            const float* ap = Arow + (size_t)(2 * P) * HW;
            h2 a = bch2(pkh2(ap[0], ap[HW]));   // (ch 2P, ch 2P+1) at (x,y)
            // storage col (lx+2) == global col x-2 (window start)
            const uint32_t* bp = &lds[plane * PSTR + ly * RSTR + lx + 2];
#pragma unroll
            for (int rr = 0; rr < KD; ++rr) {
                const uint32_t* rp = bp + rr * RSTR;
                uint32_t w0 = rp[0], w1 = rp[1], w2 = rp[2], w3 = rp[3], w4 = rp[4];
                const int kb = rr * KD;
                acc[kb + 0] = dot2acc(a, bch2(w0), acc[kb + 0]);
                acc[kb + 1] = dot2acc(a, bch2(w1), acc[kb + 1]);
                acc[kb + 2] = dot2acc(a, bch2(w2), acc[kb + 2]);
                acc[kb + 3] = dot2acc(a, bch2(w3), acc[kb + 3]);
                acc[kb + 4] = dot2acc(a, bch2(w4), acc[kb + 4]);
            }
        }
    }

    // ---- reduce the 4 channel-group partials ----
#pragma unroll
    for (int k = 0; k < KK; ++k) acc[k] = cs_reduce(acc[k]);

    // ---- softmax + expected offset (mask only on border tiles) ----
    float2 r0 = interior ? softmax_eo<false>(acc, x, y)
                         : softmax_eo<true>(acc, x, y);

    if (cs == 0) {
        size_t ob = ((size_t)img * 2) * HW + (size_t)(y * W + x);
        out[ob]      = r0.x;
        out[ob + HW] = r0.y;
    }
}

extern "C" void kernel_launch(void* const* d_in, const int* in_sizes, int n_in,
                              void* d_out, int out_size, void* d_ws, size_t ws_size,
                              hipStream_t stream)
{
    const float* f0 = (const float*)d_in[0];
    const float* f1 = (const float*)d_in[1];
    const float* f2 = (const float*)d_in[2];
    float* out = (float*)d_out;

    dim3 block(256, 1, 1);
    dim3 grid(2048, 1, 1); // 8 bands x 8 img x 32 tiles of 8x8
    bam_corr_softmax_kernel<<<grid, block, 0, stream>>>(f0, f1, f2, out);
}